// Round 3
// baseline (2680.311 us; speedup 1.0000x reference)
//
#include <hip/hip_runtime.h>
#include <math.h>

#define B_ 8
#define N_ 2048
static constexpr int BN = B_ * N_;
#define L2E_ 1.4426950408889634f

#if __has_builtin(__builtin_amdgcn_exp2f)
#define FEXP2(x) __builtin_amdgcn_exp2f(x)
#else
#define FEXP2(x) exp2f(x)
#endif

// ws layout (floats): remR[B][N] | ratioL[10][B][N] | ratioR[10][B][N] | barrier(16 u32)

// -------- per-batch sense-reversing barrier over 64 co-resident WGs --------
__device__ __forceinline__ void grid_barrier(unsigned* cnt, unsigned* gen, int b, int t) {
    __syncthreads();
    if (t == 0) {
        __threadfence();   // release our global writes (agent scope, cross-XCD)
        unsigned g = __hip_atomic_load(gen + b, __ATOMIC_RELAXED, __HIP_MEMORY_SCOPE_AGENT);
        unsigned a = __hip_atomic_fetch_add(cnt + b, 1u, __ATOMIC_ACQ_REL, __HIP_MEMORY_SCOPE_AGENT);
        if (a == 63u) {
            __hip_atomic_store(cnt + b, 0u, __ATOMIC_RELAXED, __HIP_MEMORY_SCOPE_AGENT);
            __hip_atomic_fetch_add(gen + b, 1u, __ATOMIC_RELEASE, __HIP_MEMORY_SCOPE_AGENT);
        } else {
            while (__hip_atomic_load(gen + b, __ATOMIC_ACQUIRE, __HIP_MEMORY_SCOPE_AGENT) == g)
                __builtin_amdgcn_s_sleep(1);
        }
    }
    __syncthreads();
    __threadfence();       // acquire: invalidate stale cached lines before refresh loads
}

// -------- one weighted pass: 4 rows (regs) x 2048 cols (LDS) --------
// MODE 0: s1 = sum exp(a)               (unweighted, remR=1 bootstrap)
// MODE 1: s1 = sum exp(a)*C[j].w
// MODE 2: s1 = sum exp(a)*C[j].w ; s2 = sum exp(a/4)*rem2[j]
// MODE 3: s1 = sum exp(a)*C[j].w ; s2[0] = sum rem2[j]          (level-8 fusion, W9=1)
template<int MODE>
__device__ __forceinline__ void do_pass(
    const float4* __restrict__ C, const float* __restrict__ rem2,
    float cA, float skipTh,
    const float qx[4], const float qy[4], const float qz[4],
    int lane, float s1[4], float s2[4])
{
    #pragma unroll
    for (int r = 0; r < 4; ++r) { s1[r] = 0.f; s2[r] = 0.f; }
    #pragma unroll 4
    for (int jj = 0; jj < 32; ++jj) {
        const int j = (lane << 5) | ((jj + lane) & 31);   // rotate -> conflict-free
        const float4 p = C[j];
        float rr = 0.f;
        if (MODE >= 2) rr = rem2[j];
        if (MODE == 3) s2[0] += rr;
        float a[4];
        #pragma unroll
        for (int r = 0; r < 4; ++r) {
            const float dx = qx[r]-p.x, dy = qy[r]-p.y, dz = qz[r]-p.z;
            a[r] = cA * fmaf(dx,dx, fmaf(dy,dy, dz*dz));  // direct form (accuracy)
        }
        const float amax = fmaxf(fmaxf(a[0],a[1]), fmaxf(a[2],a[3]));
        if (__any(amax >= skipTh)) {       // skipped terms are exact fp32 zeros
            #pragma unroll
            for (int r = 0; r < 4; ++r) {
                const float w1 = FEXP2(a[r]);
                s1[r] = (MODE == 0) ? (s1[r] + w1) : fmaf(w1, p.w, s1[r]);
                if (MODE == 2) s2[r] = fmaf(FEXP2(a[r]*0.25f), rr, s2[r]);
            }
        }
    }
    #pragma unroll
    for (int r = 0; r < 4; ++r) {
        float v = s1[r];
        #pragma unroll
        for (int s = 1; s < 64; s <<= 1) v += __shfl_xor(v, s);
        s1[r] = v;
        if (MODE == 2) {
            float u = s2[r];
            #pragma unroll
            for (int s = 1; s < 64; s <<= 1) u += __shfl_xor(u, s);
            s2[r] = u;
        }
    }
    if (MODE == 3) {
        float u = s2[0];
        #pragma unroll
        for (int s = 1; s < 64; s <<= 1) u += __shfl_xor(u, s);
        s2[0] = u;
    }
}

// -------- persistent kernel: all 10 levels, 20 phases, 19 barriers --------
__global__ __launch_bounds__(512, 4)
void emd_iter(const float* __restrict__ xyz1, const float* __restrict__ xyz2,
              float* __restrict__ ws, float* __restrict__ outCost,
              unsigned* __restrict__ bar)
{
    __shared__ float4 P1[N_];      // cloud1, .w = ratioL_l      (32 KB)
    __shared__ float4 P2[N_];      // cloud2, .w = ratioR_l      (32 KB)
    __shared__ float  REM2[N_];    // remR staged for row passes ( 8 KB)
    __shared__ float  red[8];

    float* remRg = ws;
    float* ratLg = ws + BN;
    float* ratRg = ws + 11*BN;
    unsigned* cnt = bar;
    unsigned* gen = bar + 8;

    const int wg = blockIdx.x;
    const int b = wg >> 6, wloc = wg & 63;
    const int t = threadIdx.x;
    const int wave = t >> 6, lane = t & 63;

    if (wg == 0 && t < B_) outCost[t] = 0.f;

    #pragma unroll
    for (int k = 0; k < 4; ++k) {               // stage both clouds ONCE
        const int j = t + k*512;
        const float* p1 = xyz1 + (size_t)(b*N_ + j)*3;
        const float* p2 = xyz2 + (size_t)(b*N_ + j)*3;
        P1[j] = make_float4(p1[0], p1[1], p1[2], 0.f);
        P2[j] = make_float4(p2[0], p2[1], p2[2], 0.f);
    }
    __syncthreads();

    const int rowbase = wloc*32 + wave*4;       // this wave's 4 rows/cols, all levels
    const int gbase = b*N_ + rowbase;
    float q1x[4],q1y[4],q1z[4],q2x[4],q2y[4],q2z[4];
    #pragma unroll
    for (int r = 0; r < 4; ++r) {
        float4 a = P1[rowbase+r]; q1x[r]=a.x; q1y[r]=a.y; q1z[r]=a.z;
        float4 c = P2[rowbase+r]; q2x[r]=c.x; q2y[r]=c.y; q2z[r]=c.z;
    }
    float remL[4] = {1,1,1,1}, remR[4] = {1,1,1,1}, ratL[4], ratR[4];
    float s1[4], s2[4];

    {   // A0: t1 = sum_j W0 (remR=1); ratioL0 = 1/(1e-9+t1)
        const float cA = -ldexpf(L2E_, 14);
        do_pass<0>(P2, nullptr, cA, -151.f, q1x,q1y,q1z, lane, s1, s2);
        #pragma unroll
        for (int r = 0; r < 4; ++r) ratL[r] = 1.f/(1e-9f + s1[r]);
        if (lane == 0)
            for (int r = 0; r < 4; ++r) ratLg[gbase + r] = ratL[r];
    }

    #pragma unroll 1
    for (int l = 0; l < 9; ++l) {
        const float cA = -ldexpf(L2E_, 14 - 2*l);
        // ---- B(l): col pass. t2_j = sum_i W*ratioL_i ----
        grid_barrier(cnt, gen, b, t);
        #pragma unroll
        for (int k = 0; k < 4; ++k) {
            const int j = t + k*512;
            P1[j].w = ratLg[(size_t)l*BN + b*N_ + j];
        }
        __syncthreads();
        do_pass<1>(P1, nullptr, cA, -151.f, q2x,q2y,q2z, lane, s1, s2);
        #pragma unroll
        for (int r = 0; r < 4; ++r) {
            ratR[r] = remR[r] / (1e-9f + s1[r]);
            remR[r] = fmaxf(0.f, remR[r] - ratR[r]*s1[r]);
        }
        if (lane == 0)
            for (int r = 0; r < 4; ++r) {
                ratRg[(size_t)l*BN + gbase + r] = ratR[r];
                remRg[gbase + r] = remR[r];
            }
        // ---- C(l)+A(l+1): row pass. t3 = sum W*ratioR ; t1' = sum W^(1/4)*remR ----
        grid_barrier(cnt, gen, b, t);
        #pragma unroll
        for (int k = 0; k < 4; ++k) {
            const int j = t + k*512;
            P2[j].w = ratRg[(size_t)l*BN + b*N_ + j];
            REM2[j] = remRg[b*N_ + j];
        }
        __syncthreads();
        if (l < 8) {
            do_pass<2>(P2, REM2, cA, -604.f, q1x,q1y,q1z, lane, s1, s2);
            #pragma unroll
            for (int r = 0; r < 4; ++r) {
                remL[r] = fmaxf(0.f, remL[r] - ratL[r]*s1[r]);
                ratL[r] = remL[r] / (1e-9f + s2[r]);
            }
        } else {  // l==8: next level W9==1 -> t1' = sum remR
            do_pass<3>(P2, REM2, cA, -151.f, q1x,q1y,q1z, lane, s1, s2);
            #pragma unroll
            for (int r = 0; r < 4; ++r) {
                remL[r] = fmaxf(0.f, remL[r] - ratL[r]*s1[r]);
                ratL[r] = remL[r] / (1e-9f + s2[0]);
            }
        }
        if (lane == 0)
            for (int r = 0; r < 4; ++r) ratLg[(size_t)(l+1)*BN + gbase + r] = ratL[r];
    }

    // ---- B9 (rank-1): S = sum_i ratioL9 ; ratioR9_j = remR_j/(1e-9+S) ----
    grid_barrier(cnt, gen, b, t);
    #pragma unroll
    for (int k = 0; k < 4; ++k) {
        const int j = t + k*512;
        P1[j].w = ratLg[(size_t)9*BN + b*N_ + j];
    }
    __syncthreads();
    float s = 0.f;
    #pragma unroll
    for (int k = 0; k < 4; ++k) s += P1[t + k*512].w;
    #pragma unroll
    for (int d = 1; d < 64; d <<= 1) s += __shfl_xor(s, d);
    if (lane == 0) red[wave] = s;
    __syncthreads();
    const float S = ((red[0]+red[1])+(red[2]+red[3]))+((red[4]+red[5])+(red[6]+red[7]));
    const float inv = 1.f/(1e-9f + S);
    if (lane == 0)
        for (int r = 0; r < 4; ++r)
            ratRg[(size_t)9*BN + gbase + r] = remR[r]*inv;
}

// -------- match + cost emission (unchanged structure, direct-form sqd) --------
static constexpr int JCH = 32;

__global__ __launch_bounds__(256, 4)
void match_kernel(const float* __restrict__ xyz1, const float* __restrict__ xyz2,
                  const float* __restrict__ ws, float* __restrict__ out, float c8)
{
    __shared__ float4 pts[JCH];
    __shared__ __align__(16) float rrs[JCH][12];
    __shared__ float cred[4];

    const float* ratL = ws + BN;
    const float* ratR = ws + 11*BN;
    float* outCost  = out;
    float* outMatch = out + B_;

    const int wg = blockIdx.x;          // b(8) x ic(2) x jc(64)
    const int b  = wg >> 7;
    const int ic = (wg >> 6) & 1;
    const int jc = wg & 63;
    const int t  = threadIdx.x;
    const int jbase = jc * JCH;

    if (t < JCH) {
        const float* p = xyz2 + (size_t)(b*N_ + jbase + t)*3;
        pts[t] = make_float4(p[0], p[1], p[2], 0.f);
    }
    for (int k = t; k < 10*JCH; k += 256) {
        const int l = k >> 5, ji = k & 31;
        rrs[ji][l] = ratR[(size_t)l*BN + b*N_ + jbase + ji];
    }

    float qx[4], qy[4], qz[4], RL[4][10];
    #pragma unroll
    for (int k = 0; k < 4; ++k) {
        const int i = ic*1024 + k*256 + t;
        const float* q = xyz1 + (size_t)(b*N_ + i)*3;
        qx[k] = q[0]; qy[k] = q[1]; qz[k] = q[2];
        #pragma unroll
        for (int l = 0; l < 10; ++l) RL[k][l] = ratL[(size_t)l*BN + b*N_ + i];
    }
    __syncthreads();

    float cost = 0.f;
    const size_t ob0 = (size_t)b*N_*N_ + (size_t)jbase*N_ + (size_t)(ic*1024) + t;

    for (int jj = 0; jj < JCH; ++jj) {
        const float4 p  = pts[jj];
        const float4 rA = *(const float4*)&rrs[jj][0];
        const float4 rB = *(const float4*)&rrs[jj][4];
        const float4 rC = *(const float4*)&rrs[jj][8];
        float a[4], m[4], sd[4];
        #pragma unroll
        for (int k = 0; k < 4; ++k) {
            const float dx = qx[k]-p.x, dy = qy[k]-p.y, dz = qz[k]-p.z;
            const float sqd = fmaf(dx,dx, fmaf(dy,dy, dz*dz));
            a[k]  = c8 * sqd;
            sd[k] = sqrtf(sqd);
            m[k]  = RL[k][9] * rC.y;               // level 9: W = 1
        }
        #define DL(lv, rv) { _Pragma("unroll") \
            for (int k = 0; k < 4; ++k) { \
                m[k] = fmaf(FEXP2(a[k]) * RL[k][lv], rv, m[k]); a[k] *= 4.0f; } }
        #define ALIVE __any(fmaxf(fmaxf(a[0],a[1]), fmaxf(a[2],a[3])) >= -151.0f)
        DL(8, rC.x)
        if (ALIVE) { DL(7, rB.w)
         if (ALIVE) { DL(6, rB.z)
          if (ALIVE) { DL(5, rB.y)
           if (ALIVE) { DL(4, rB.x)
            if (ALIVE) { DL(3, rA.w)
             if (ALIVE) { DL(2, rA.z)
              if (ALIVE) { DL(1, rA.y)
               if (ALIVE) { DL(0, rA.x) } } } } } } } }
        #undef DL
        #undef ALIVE
        #pragma unroll
        for (int k = 0; k < 4; ++k) {
            __builtin_nontemporal_store(m[k], &outMatch[ob0 + (size_t)jj*N_ + k*256]);
            cost = fmaf(m[k], sd[k], cost);
        }
    }

    #pragma unroll
    for (int s = 1; s < 64; s <<= 1) cost += __shfl_xor(cost, s);
    const int wave = t >> 6, lane = t & 63;
    if (lane == 0) cred[wave] = cost;
    __syncthreads();
    if (t == 0) atomicAdd(outCost + b, cred[0]+cred[1]+cred[2]+cred[3]);
}

extern "C" void kernel_launch(void* const* d_in, const int* in_sizes, int n_in,
                              void* d_out, int out_size, void* d_ws, size_t ws_size,
                              hipStream_t stream) {
    const float* xyz1 = (const float*)d_in[0];
    const float* xyz2 = (const float*)d_in[1];
    float* out = (float*)d_out;
    float* ws  = (float*)d_ws;
    unsigned* bar = (unsigned*)(ws + 21*BN);

    hipMemsetAsync(bar, 0, 16*sizeof(unsigned), stream);   // barrier state
    emd_iter<<<dim3(512), dim3(512), 0, stream>>>(xyz1, xyz2, ws, out, bar);
    const float c8 = -(float)(0.25 * 1.4426950408889634);
    match_kernel<<<dim3(B_*128), dim3(256), 0, stream>>>(xyz1, xyz2, ws, out, c8);
}

// Round 6
// 970.270 us; speedup vs baseline: 2.7624x; 2.7624x over previous
//
#include <hip/hip_runtime.h>
#include <math.h>

#define B_ 8
#define N_ 2048
static constexpr int BN = B_ * N_;
#define L2E_ 1.4426950408889634f

#if __has_builtin(__builtin_amdgcn_exp2f)
#define FEXP2(x) __builtin_amdgcn_exp2f(x)
#else
#define FEXP2(x) exp2f(x)
#endif

// ws layout (floats):
//   remR[B][N] | ratioL[10][B][N] | ratioR[9][B][N] | S[8] | cnt[8] | gen[8]
// S/cnt/gen zeroed by hipMemsetAsync each call.

// ---- per-batch sense-reversing barrier over 64 co-resident WGs ----
// ALL cross-WG signals are atomic RMWs: RMWs execute at the device coherence
// point (cross-XCD safe), unlike relaxed plain stores/loads which can sit in /
// read from a non-coherent per-XCD L2 (round-5 deadlock). Exactly one release
// fence (wbl2) at arrival and one acquire fence (inv) at wake, leader only.
__device__ __forceinline__ void grid_barrier(unsigned* cnt, unsigned* gen, int b, int t) {
    __syncthreads();
    if (t == 0) {
        __builtin_amdgcn_fence(__ATOMIC_RELEASE, "agent");   // push our global writes
        unsigned g = __hip_atomic_fetch_add(gen + b, 0u, __ATOMIC_RELAXED, __HIP_MEMORY_SCOPE_AGENT);
        unsigned a = __hip_atomic_fetch_add(cnt + b, 1u, __ATOMIC_RELAXED, __HIP_MEMORY_SCOPE_AGENT);
        if (a == 63u) {
            __hip_atomic_fetch_add(cnt + b, (unsigned)-64, __ATOMIC_RELAXED, __HIP_MEMORY_SCOPE_AGENT);
            __hip_atomic_fetch_add(gen + b, 1u, __ATOMIC_RELAXED, __HIP_MEMORY_SCOPE_AGENT);
        } else {
            int guard = 0;
            while (__hip_atomic_fetch_add(gen + b, 0u, __ATOMIC_RELAXED, __HIP_MEMORY_SCOPE_AGENT) == g) {
                __builtin_amdgcn_s_sleep(8);
                if (++guard > 200000) break;   // bounded: wrong-but-diagnosable, never hangs
            }
        }
        __builtin_amdgcn_fence(__ATOMIC_ACQUIRE, "agent");   // invalidate stale L1/L2
    }
    __syncthreads();
}

// -------- one weighted pass: 4 rows (regs) x 2048 cols (LDS) --------
// MODE 0: s1 = sum exp(a)                (bootstrap, weights=1)
// MODE 1: s1 = sum exp(a)*C[j].w
// MODE 2: s1 = sum exp(a)*C[j].w ; s2 = sum exp(a/4)*rem2[j]
// MODE 3: s1 = sum exp(a)*C[j].w ; s2[0] = sum rem2[j]   (l=8 fusion, W9=1)
template<int MODE>
__device__ __forceinline__ void do_pass(
    const float4* __restrict__ C, const float* __restrict__ rem2,
    float cA, float skipTh,
    const float qx[4], const float qy[4], const float qz[4],
    int lane, float s1[4], float s2[4])
{
    #pragma unroll
    for (int r = 0; r < 4; ++r) { s1[r] = 0.f; s2[r] = 0.f; }
    #pragma unroll 4
    for (int jj = 0; jj < 32; ++jj) {
        const int j = (jj << 6) | lane;          // stride-1 -> conflict-free b128
        const float4 p = C[j];
        float rr = 0.f;
        if (MODE >= 2) rr = rem2[j];
        if (MODE == 3) s2[0] += rr;
        float a[4];
        #pragma unroll
        for (int r = 0; r < 4; ++r) {
            const float dx = qx[r]-p.x, dy = qy[r]-p.y, dz = qz[r]-p.z;
            a[r] = cA * fmaf(dx,dx, fmaf(dy,dy, dz*dz));  // direct form (accuracy)
        }
        const float amax = fmaxf(fmaxf(a[0],a[1]), fmaxf(a[2],a[3]));
        if (__any(amax >= skipTh)) {             // skipped terms are exact fp32 zeros
            #pragma unroll
            for (int r = 0; r < 4; ++r) {
                const float w1 = FEXP2(a[r]);
                s1[r] = (MODE == 0) ? (s1[r] + w1) : fmaf(w1, p.w, s1[r]);
                if (MODE == 2) s2[r] = fmaf(FEXP2(a[r]*0.25f), rr, s2[r]);
            }
        }
    }
    #pragma unroll
    for (int r = 0; r < 4; ++r) {
        float v = s1[r];
        #pragma unroll
        for (int s = 1; s < 64; s <<= 1) v += __shfl_xor(v, s);
        s1[r] = v;
        if (MODE == 2) {
            float u = s2[r];
            #pragma unroll
            for (int s = 1; s < 64; s <<= 1) u += __shfl_xor(u, s);
            s2[r] = u;
        }
    }
    if (MODE == 3) {
        float u = s2[0];
        #pragma unroll
        for (int s = 1; s < 64; s <<= 1) u += __shfl_xor(u, s);
        s2[0] = u;
    }
}

// ---- persistent kernel: 19 phases, 18 barriers; level-9 col pass via atomicAdd ----
__global__ __launch_bounds__(512, 4)
void emd_iter(const float* __restrict__ xyz1, const float* __restrict__ xyz2,
              float* __restrict__ ws, float* __restrict__ outCost,
              float* __restrict__ Sg, unsigned* __restrict__ bar)
{
    __shared__ float4 P1[N_];      // cloud1, .w = ratioL_l      (32 KB)
    __shared__ float4 P2[N_];      // cloud2, .w = ratioR_l      (32 KB)
    __shared__ float  REM2[N_];    // remR staged for row passes ( 8 KB)

    float* remRg = ws;
    float* ratLg = ws + BN;
    float* ratRg = ws + 11*BN;
    unsigned* cnt = bar;
    unsigned* gen = bar + 8;

    const int wg = blockIdx.x;
    const int b = wg >> 6, wloc = wg & 63;
    const int t = threadIdx.x;
    const int wave = t >> 6, lane = t & 63;

    if (wg == 0 && t < B_) outCost[t] = 0.f;

    #pragma unroll
    for (int k = 0; k < 4; ++k) {               // stage both clouds ONCE
        const int j = t + k*512;
        const float* p1 = xyz1 + (size_t)(b*N_ + j)*3;
        const float* p2 = xyz2 + (size_t)(b*N_ + j)*3;
        P1[j] = make_float4(p1[0], p1[1], p1[2], 0.f);
        P2[j] = make_float4(p2[0], p2[1], p2[2], 0.f);
    }
    __syncthreads();

    const int rowbase = wloc*32 + wave*4;       // this wave's 4 rows/cols, all levels
    const int gbase = b*N_ + rowbase;
    float q1x[4],q1y[4],q1z[4],q2x[4],q2y[4],q2z[4];
    #pragma unroll
    for (int r = 0; r < 4; ++r) {
        float4 a = P1[rowbase+r]; q1x[r]=a.x; q1y[r]=a.y; q1z[r]=a.z;
        float4 c = P2[rowbase+r]; q2x[r]=c.x; q2y[r]=c.y; q2z[r]=c.z;
    }
    float remL[4] = {1,1,1,1}, remR[4] = {1,1,1,1}, ratL[4], ratR[4];
    float s1[4], s2[4];

    {   // A0: t1 = sum_j W0 (remR=1); ratioL0 = 1/(1e-9+t1)
        const float cA = -ldexpf(L2E_, 14);
        do_pass<0>(P2, nullptr, cA, -151.f, q1x,q1y,q1z, lane, s1, s2);
        #pragma unroll
        for (int r = 0; r < 4; ++r) ratL[r] = 1.f/(1e-9f + s1[r]);
        if (lane == 0)
            for (int r = 0; r < 4; ++r) ratLg[gbase + r] = ratL[r];
    }

    #pragma unroll 1
    for (int l = 0; l < 9; ++l) {
        const float cA = -ldexpf(L2E_, 14 - 2*l);
        // ---- B(l): col pass. t2_j = sum_i W*ratioL_i ----
        grid_barrier(cnt, gen, b, t);
        #pragma unroll
        for (int k = 0; k < 4; ++k) {
            const int j = t + k*512;
            P1[j].w = ratLg[(size_t)l*BN + b*N_ + j];
        }
        __syncthreads();
        do_pass<1>(P1, nullptr, cA, -151.f, q2x,q2y,q2z, lane, s1, s2);
        #pragma unroll
        for (int r = 0; r < 4; ++r) {
            ratR[r] = remR[r] / (1e-9f + s1[r]);
            remR[r] = fmaxf(0.f, remR[r] - ratR[r]*s1[r]);
        }
        if (lane == 0)
            for (int r = 0; r < 4; ++r) {
                ratRg[(size_t)l*BN + gbase + r] = ratR[r];
                remRg[gbase + r] = remR[r];
            }
        // ---- C(l)+A(l+1): row pass. t3 = sum W*ratioR ; t1' = sum W^(1/4)*remR ----
        grid_barrier(cnt, gen, b, t);
        #pragma unroll
        for (int k = 0; k < 4; ++k) {
            const int j = t + k*512;
            P2[j].w = ratRg[(size_t)l*BN + b*N_ + j];
            REM2[j] = remRg[b*N_ + j];
        }
        __syncthreads();
        if (l < 8) {
            do_pass<2>(P2, REM2, cA, -604.f, q1x,q1y,q1z, lane, s1, s2);
            #pragma unroll
            for (int r = 0; r < 4; ++r) {
                remL[r] = fmaxf(0.f, remL[r] - ratL[r]*s1[r]);
                ratL[r] = remL[r] / (1e-9f + s2[r]);
            }
        } else {  // l==8: next level W9==1 -> t1' = sum remR
            do_pass<3>(P2, REM2, cA, -151.f, q1x,q1y,q1z, lane, s1, s2);
            #pragma unroll
            for (int r = 0; r < 4; ++r) {
                remL[r] = fmaxf(0.f, remL[r] - ratL[r]*s1[r]);
                ratL[r] = remL[r] / (1e-9f + s2[0]);
            }
        }
        if (lane == 0)
            for (int r = 0; r < 4; ++r) ratLg[(size_t)(l+1)*BN + gbase + r] = ratL[r];
    }

    // level-9 col pass is rank-1: contribute partial S = sum_i ratioL9_i.
    // (match kernel computes ratioR9_j = remR_j/(1e-9+S) on the fly)
    if (lane == 0)
        atomicAdd(Sg + b, ((ratL[0]+ratL[1]) + (ratL[2]+ratL[3])));
}

// -------- match + cost emission --------
static constexpr int JCH = 32;

__global__ __launch_bounds__(256, 4)
void match_kernel(const float* __restrict__ xyz1, const float* __restrict__ xyz2,
                  const float* __restrict__ ws, float* __restrict__ out, float c8)
{
    __shared__ float4 pts[JCH];
    __shared__ __align__(16) float rrs[JCH][12];
    __shared__ float cred[4];

    const float* remRg = ws;
    const float* ratL  = ws + BN;
    const float* ratR  = ws + 11*BN;
    const float* Sg    = ws + 20*BN;
    float* outCost  = out;
    float* outMatch = out + B_;

    const int wg = blockIdx.x;          // b(8) x ic(2) x jc(64)
    const int b  = wg >> 7;
    const int ic = (wg >> 6) & 1;
    const int jc = wg & 63;
    const int t  = threadIdx.x;
    const int jbase = jc * JCH;

    const float invS = 1.0f / (1e-9f + Sg[b]);

    if (t < JCH) {
        const float* p = xyz2 + (size_t)(b*N_ + jbase + t)*3;
        pts[t] = make_float4(p[0], p[1], p[2], 0.f);
    }
    for (int k = t; k < 10*JCH; k += 256) {
        const int l = k >> 5, ji = k & 31;
        rrs[ji][l] = (l == 9) ? remRg[b*N_ + jbase + ji] * invS
                              : ratR[(size_t)l*BN + b*N_ + jbase + ji];
    }

    float qx[4], qy[4], qz[4], RL[4][10];
    #pragma unroll
    for (int k = 0; k < 4; ++k) {
        const int i = ic*1024 + k*256 + t;
        const float* q = xyz1 + (size_t)(b*N_ + i)*3;
        qx[k] = q[0]; qy[k] = q[1]; qz[k] = q[2];
        #pragma unroll
        for (int l = 0; l < 10; ++l) RL[k][l] = ratL[(size_t)l*BN + b*N_ + i];
    }
    __syncthreads();

    float cost = 0.f;
    const size_t ob0 = (size_t)b*N_*N_ + (size_t)jbase*N_ + (size_t)(ic*1024) + t;

    for (int jj = 0; jj < JCH; ++jj) {
        const float4 p  = pts[jj];
        const float4 rA = *(const float4*)&rrs[jj][0];
        const float4 rB = *(const float4*)&rrs[jj][4];
        const float4 rC = *(const float4*)&rrs[jj][8];
        float a[4], m[4], sd[4];
        #pragma unroll
        for (int k = 0; k < 4; ++k) {
            const float dx = qx[k]-p.x, dy = qy[k]-p.y, dz = qz[k]-p.z;
            const float sqd = fmaf(dx,dx, fmaf(dy,dy, dz*dz));
            a[k]  = c8 * sqd;
            sd[k] = sqrtf(sqd);
            m[k]  = RL[k][9] * rC.y;               // level 9: W = 1
        }
        #define DL(lv, rv) { _Pragma("unroll") \
            for (int k = 0; k < 4; ++k) { \
                m[k] = fmaf(FEXP2(a[k]) * RL[k][lv], rv, m[k]); a[k] *= 4.0f; } }
        #define ALIVE __any(fmaxf(fmaxf(a[0],a[1]), fmaxf(a[2],a[3])) >= -151.0f)
        DL(8, rC.x)
        if (ALIVE) { DL(7, rB.w)
         if (ALIVE) { DL(6, rB.z)
          if (ALIVE) { DL(5, rB.y)
           if (ALIVE) { DL(4, rB.x)
            if (ALIVE) { DL(3, rA.w)
             if (ALIVE) { DL(2, rA.z)
              if (ALIVE) { DL(1, rA.y)
               if (ALIVE) { DL(0, rA.x) } } } } } } } }
        #undef DL
        #undef ALIVE
        #pragma unroll
        for (int k = 0; k < 4; ++k) {
            __builtin_nontemporal_store(m[k], &outMatch[ob0 + (size_t)jj*N_ + k*256]);
            cost = fmaf(m[k], sd[k], cost);
        }
    }

    #pragma unroll
    for (int s = 1; s < 64; s <<= 1) cost += __shfl_xor(cost, s);
    const int wave = t >> 6, lane = t & 63;
    if (lane == 0) cred[wave] = cost;
    __syncthreads();
    if (t == 0) atomicAdd(outCost + b, cred[0]+cred[1]+cred[2]+cred[3]);
}

extern "C" void kernel_launch(void* const* d_in, const int* in_sizes, int n_in,
                              void* d_out, int out_size, void* d_ws, size_t ws_size,
                              hipStream_t stream) {
    const float* xyz1 = (const float*)d_in[0];
    const float* xyz2 = (const float*)d_in[1];
    float* out = (float*)d_out;
    float* ws  = (float*)d_ws;
    float* Sg  = ws + 20*BN;                 // 8 floats
    unsigned* bar = (unsigned*)(Sg + 8);     // cnt[8] | gen[8]

    hipMemsetAsync(Sg, 0, 24*sizeof(unsigned), stream);   // S + barrier state
    emd_iter<<<dim3(512), dim3(512), 0, stream>>>(xyz1, xyz2, ws, out, Sg, bar);
    const float c8 = -(float)(0.25 * 1.4426950408889634);
    match_kernel<<<dim3(B_*128), dim3(256), 0, stream>>>(xyz1, xyz2, ws, out, c8);
}

// Round 7
// 803.494 us; speedup vs baseline: 3.3358x; 1.2076x over previous
//
#include <hip/hip_runtime.h>
#include <math.h>

#define B_ 8
#define N_ 2048
static constexpr int BN = B_ * N_;
#define L2E_ 1.4426950408889634f

#if __has_builtin(__builtin_amdgcn_exp2f)
#define FEXP2(x) __builtin_amdgcn_exp2f(x)
#else
#define FEXP2(x) exp2f(x)
#endif

// Wait until this wave's outstanding vmem ops (atomicExch publishes) have
// COMPLETED at the coherence point. Must run before the barrier arrive-RMW.
#define VM_DRAIN() asm volatile("s_waitcnt vmcnt(0)" ::: "memory")

// ws layout (floats):
//   ratioL[10][B][N] | ratioR[9][B][N] | remR_lv[9][B][N] | S[8] | cnt[8] | gen[8]
// Every exchanged address is written EXACTLY ONCE (atomicExch -> coherence
// point) and read only AFTER the barrier -> readers' caches can never hold a
// stale copy -> no release/acquire fences anywhere (round-6's 690us of
// wbl2/inv storms deleted).

// ---- per-batch sense-reversing barrier over 64 co-resident WGs ----
// All signals are atomic RMWs (execute at device coherence point, cross-XCD
// safe). NO cache-maintenance fences.
__device__ __forceinline__ void grid_barrier(unsigned* cnt, unsigned* gen, int b, int t) {
    __syncthreads();
    if (t == 0) {
        unsigned g = __hip_atomic_fetch_add(gen + b, 0u, __ATOMIC_RELAXED, __HIP_MEMORY_SCOPE_AGENT);
        unsigned a = __hip_atomic_fetch_add(cnt + b, 1u, __ATOMIC_RELAXED, __HIP_MEMORY_SCOPE_AGENT);
        if (a == 63u) {
            __hip_atomic_fetch_add(cnt + b, (unsigned)-64, __ATOMIC_RELAXED, __HIP_MEMORY_SCOPE_AGENT);
            __hip_atomic_fetch_add(gen + b, 1u, __ATOMIC_RELAXED, __HIP_MEMORY_SCOPE_AGENT);
        } else {
            int guard = 0;
            while (__hip_atomic_fetch_add(gen + b, 0u, __ATOMIC_RELAXED, __HIP_MEMORY_SCOPE_AGENT) == g) {
                __builtin_amdgcn_s_sleep(4);
                if (++guard > 200000) break;   // bounded: diagnosable, never hangs
            }
        }
    }
    __syncthreads();
}

// -------- one weighted pass: 4 rows (regs) x 2048 cols (LDS) --------
// MODE 0: s1 = sum exp(a)                (bootstrap, weights=1)
// MODE 1: s1 = sum exp(a)*C[j].w
// MODE 2: s1 = sum exp(a)*C[j].w ; s2 = sum exp(a/4)*rem2[j]
// MODE 3: s1 = sum exp(a)*C[j].w ; s2[0] = sum rem2[j]   (l=8 fusion, W9=1)
template<int MODE>
__device__ __forceinline__ void do_pass(
    const float4* __restrict__ C, const float* __restrict__ rem2,
    float cA, float skipTh,
    const float qx[4], const float qy[4], const float qz[4],
    int lane, float s1[4], float s2[4])
{
    #pragma unroll
    for (int r = 0; r < 4; ++r) { s1[r] = 0.f; s2[r] = 0.f; }
    #pragma unroll 4
    for (int jj = 0; jj < 32; ++jj) {
        const int j = (jj << 6) | lane;          // stride-1 b128 (conflict-free)
        const float4 p = C[j];
        float rr = 0.f;
        if (MODE >= 2) rr = rem2[j];
        if (MODE == 3) s2[0] += rr;
        float a[4];
        #pragma unroll
        for (int r = 0; r < 4; ++r) {
            const float dx = qx[r]-p.x, dy = qy[r]-p.y, dz = qz[r]-p.z;
            a[r] = cA * fmaf(dx,dx, fmaf(dy,dy, dz*dz));  // direct form (accuracy)
        }
        const float amax = fmaxf(fmaxf(a[0],a[1]), fmaxf(a[2],a[3]));
        if (__any(amax >= skipTh)) {             // skipped terms are exact fp32 zeros
            #pragma unroll
            for (int r = 0; r < 4; ++r) {
                const float w1 = FEXP2(a[r]);
                s1[r] = (MODE == 0) ? (s1[r] + w1) : fmaf(w1, p.w, s1[r]);
                if (MODE == 2) s2[r] = fmaf(FEXP2(a[r]*0.25f), rr, s2[r]);
            }
        }
    }
    #pragma unroll
    for (int r = 0; r < 4; ++r) {
        float v = s1[r];
        #pragma unroll
        for (int s = 1; s < 64; s <<= 1) v += __shfl_xor(v, s);
        s1[r] = v;
        if (MODE == 2) {
            float u = s2[r];
            #pragma unroll
            for (int s = 1; s < 64; s <<= 1) u += __shfl_xor(u, s);
            s2[r] = u;
        }
    }
    if (MODE == 3) {
        float u = s2[0];
        #pragma unroll
        for (int s = 1; s < 64; s <<= 1) u += __shfl_xor(u, s);
        s2[0] = u;
    }
}

// ---- persistent kernel: 19 phases, 18 fence-free barriers ----
__global__ __launch_bounds__(512, 4)
void emd_iter(const float* __restrict__ xyz1, const float* __restrict__ xyz2,
              float* __restrict__ ws, float* __restrict__ outCost,
              float* __restrict__ Sg, unsigned* __restrict__ bar)
{
    __shared__ float4 P1[N_];      // cloud1, .w = ratioL_l      (32 KB)
    __shared__ float4 P2[N_];      // cloud2, .w = ratioR_l      (32 KB)
    __shared__ float  REM2[N_];    // remR_l staged for row passes( 8 KB)

    float* ratLg = ws;                    // [10][BN]
    float* ratRg = ws + 10*BN;            // [9][BN]
    float* remRg = ws + 19*BN;            // [9][BN]  per-level ping-pong
    unsigned* cnt = bar;
    unsigned* gen = bar + 8;

    const int wg = blockIdx.x;
    const int b = wg >> 6, wloc = wg & 63;
    const int t = threadIdx.x;
    const int wave = t >> 6, lane = t & 63;

    if (wg == 0 && t < B_) outCost[t] = 0.f;    // flushed at kernel end (dispatch release)

    #pragma unroll
    for (int k = 0; k < 4; ++k) {               // stage both clouds ONCE
        const int j = t + k*512;
        const float* p1 = xyz1 + (size_t)(b*N_ + j)*3;
        const float* p2 = xyz2 + (size_t)(b*N_ + j)*3;
        P1[j] = make_float4(p1[0], p1[1], p1[2], 0.f);
        P2[j] = make_float4(p2[0], p2[1], p2[2], 0.f);
    }
    __syncthreads();

    const int rowbase = wloc*32 + wave*4;       // this wave's 4 rows/cols, all levels
    const int gbase = b*N_ + rowbase;
    float q1x[4],q1y[4],q1z[4],q2x[4],q2y[4],q2z[4];
    #pragma unroll
    for (int r = 0; r < 4; ++r) {
        float4 a = P1[rowbase+r]; q1x[r]=a.x; q1y[r]=a.y; q1z[r]=a.z;
        float4 c = P2[rowbase+r]; q2x[r]=c.x; q2y[r]=c.y; q2z[r]=c.z;
    }
    float remL[4] = {1,1,1,1}, remR[4] = {1,1,1,1}, ratL[4], ratR[4];
    float s1[4], s2[4];

    {   // A0: t1 = sum_j W0 (remR=1); ratioL0 = 1/(1e-9+t1)
        const float cA = -ldexpf(L2E_, 14);
        do_pass<0>(P2, nullptr, cA, -151.f, q1x,q1y,q1z, lane, s1, s2);
        #pragma unroll
        for (int r = 0; r < 4; ++r) ratL[r] = 1.f/(1e-9f + s1[r]);
        if (lane == 0)
            for (int r = 0; r < 4; ++r) atomicExch(ratLg + gbase + r, ratL[r]);
        VM_DRAIN();
    }

    #pragma unroll 1
    for (int l = 0; l < 9; ++l) {
        const float cA = -ldexpf(L2E_, 14 - 2*l);
        // ---- B(l): col pass. t2_j = sum_i W*ratioL_i ----
        grid_barrier(cnt, gen, b, t);
        #pragma unroll
        for (int k = 0; k < 4; ++k) {
            const int j = t + k*512;
            P1[j].w = ratLg[(size_t)l*BN + b*N_ + j];     // fresh addr: plain load OK
        }
        __syncthreads();
        do_pass<1>(P1, nullptr, cA, -151.f, q2x,q2y,q2z, lane, s1, s2);
        #pragma unroll
        for (int r = 0; r < 4; ++r) {
            ratR[r] = remR[r] / (1e-9f + s1[r]);
            remR[r] = fmaxf(0.f, remR[r] - ratR[r]*s1[r]);
        }
        if (lane == 0)
            for (int r = 0; r < 4; ++r) {
                atomicExch(ratRg + (size_t)l*BN + gbase + r, ratR[r]);
                atomicExch(remRg + (size_t)l*BN + gbase + r, remR[r]);
            }
        VM_DRAIN();
        // ---- C(l)+A(l+1): row pass. t3 = sum W*ratioR ; t1' = sum W^(1/4)*remR ----
        grid_barrier(cnt, gen, b, t);
        #pragma unroll
        for (int k = 0; k < 4; ++k) {
            const int j = t + k*512;
            P2[j].w = ratRg[(size_t)l*BN + b*N_ + j];     // fresh addrs: plain loads OK
            REM2[j] = remRg[(size_t)l*BN + b*N_ + j];
        }
        __syncthreads();
        if (l < 8) {
            do_pass<2>(P2, REM2, cA, -604.f, q1x,q1y,q1z, lane, s1, s2);
            #pragma unroll
            for (int r = 0; r < 4; ++r) {
                remL[r] = fmaxf(0.f, remL[r] - ratL[r]*s1[r]);
                ratL[r] = remL[r] / (1e-9f + s2[r]);
            }
        } else {  // l==8: next level W9==1 -> t1' = sum remR
            do_pass<3>(P2, REM2, cA, -151.f, q1x,q1y,q1z, lane, s1, s2);
            #pragma unroll
            for (int r = 0; r < 4; ++r) {
                remL[r] = fmaxf(0.f, remL[r] - ratL[r]*s1[r]);
                ratL[r] = remL[r] / (1e-9f + s2[0]);
            }
        }
        if (lane == 0)
            for (int r = 0; r < 4; ++r)
                atomicExch(ratLg + (size_t)(l+1)*BN + gbase + r, ratL[r]);
        VM_DRAIN();
    }

    // level-9 col pass is rank-1: contribute partial S = sum_i ratioL9_i.
    // (match kernel computes ratioR9_j = remR8_j/(1e-9+S) on the fly)
    if (lane == 0)
        atomicAdd(Sg + b, ((ratL[0]+ratL[1]) + (ratL[2]+ratL[3])));
}

// -------- match + cost emission --------
static constexpr int JCH = 32;

__global__ __launch_bounds__(256, 4)
void match_kernel(const float* __restrict__ xyz1, const float* __restrict__ xyz2,
                  const float* __restrict__ ws, float* __restrict__ out, float c8)
{
    __shared__ float4 pts[JCH];
    __shared__ __align__(16) float rrs[JCH][12];
    __shared__ float cred[4];

    const float* ratL  = ws;
    const float* ratR  = ws + 10*BN;
    const float* remR8 = ws + 19*BN + (size_t)8*BN;
    const float* Sg    = ws + 28*BN;
    float* outCost  = out;
    float* outMatch = out + B_;

    const int wg = blockIdx.x;          // b(8) x ic(2) x jc(64)
    const int b  = wg >> 7;
    const int ic = (wg >> 6) & 1;
    const int jc = wg & 63;
    const int t  = threadIdx.x;
    const int jbase = jc * JCH;

    const float invS = 1.0f / (1e-9f + Sg[b]);

    if (t < JCH) {
        const float* p = xyz2 + (size_t)(b*N_ + jbase + t)*3;
        pts[t] = make_float4(p[0], p[1], p[2], 0.f);
    }
    for (int k = t; k < 10*JCH; k += 256) {
        const int l = k >> 5, ji = k & 31;
        rrs[ji][l] = (l == 9) ? remR8[b*N_ + jbase + ji] * invS
                              : ratR[(size_t)l*BN + b*N_ + jbase + ji];
    }

    float qx[4], qy[4], qz[4], RL[4][10];
    #pragma unroll
    for (int k = 0; k < 4; ++k) {
        const int i = ic*1024 + k*256 + t;
        const float* q = xyz1 + (size_t)(b*N_ + i)*3;
        qx[k] = q[0]; qy[k] = q[1]; qz[k] = q[2];
        #pragma unroll
        for (int l = 0; l < 10; ++l) RL[k][l] = ratL[(size_t)l*BN + b*N_ + i];
    }
    __syncthreads();

    float cost = 0.f;
    const size_t ob0 = (size_t)b*N_*N_ + (size_t)jbase*N_ + (size_t)(ic*1024) + t;

    for (int jj = 0; jj < JCH; ++jj) {
        const float4 p  = pts[jj];
        const float4 rA = *(const float4*)&rrs[jj][0];
        const float4 rB = *(const float4*)&rrs[jj][4];
        const float4 rC = *(const float4*)&rrs[jj][8];
        float a[4], m[4], sd[4];
        #pragma unroll
        for (int k = 0; k < 4; ++k) {
            const float dx = qx[k]-p.x, dy = qy[k]-p.y, dz = qz[k]-p.z;
            const float sqd = fmaf(dx,dx, fmaf(dy,dy, dz*dz));
            a[k]  = c8 * sqd;
            sd[k] = sqrtf(sqd);
            m[k]  = RL[k][9] * rC.y;               // level 9: W = 1
        }
        #define DL(lv, rv) { _Pragma("unroll") \
            for (int k = 0; k < 4; ++k) { \
                m[k] = fmaf(FEXP2(a[k]) * RL[k][lv], rv, m[k]); a[k] *= 4.0f; } }
        #define ALIVE __any(fmaxf(fmaxf(a[0],a[1]), fmaxf(a[2],a[3])) >= -151.0f)
        DL(8, rC.x)
        if (ALIVE) { DL(7, rB.w)
         if (ALIVE) { DL(6, rB.z)
          if (ALIVE) { DL(5, rB.y)
           if (ALIVE) { DL(4, rB.x)
            if (ALIVE) { DL(3, rA.w)
             if (ALIVE) { DL(2, rA.z)
              if (ALIVE) { DL(1, rA.y)
               if (ALIVE) { DL(0, rA.x) } } } } } } } }
        #undef DL
        #undef ALIVE
        #pragma unroll
        for (int k = 0; k < 4; ++k) {
            __builtin_nontemporal_store(m[k], &outMatch[ob0 + (size_t)jj*N_ + k*256]);
            cost = fmaf(m[k], sd[k], cost);
        }
    }

    #pragma unroll
    for (int s = 1; s < 64; s <<= 1) cost += __shfl_xor(cost, s);
    const int wave = t >> 6, lane = t & 63;
    if (lane == 0) cred[wave] = cost;
    __syncthreads();
    if (t == 0) atomicAdd(outCost + b, cred[0]+cred[1]+cred[2]+cred[3]);
}

extern "C" void kernel_launch(void* const* d_in, const int* in_sizes, int n_in,
                              void* d_out, int out_size, void* d_ws, size_t ws_size,
                              hipStream_t stream) {
    const float* xyz1 = (const float*)d_in[0];
    const float* xyz2 = (const float*)d_in[1];
    float* out = (float*)d_out;
    float* ws  = (float*)d_ws;
    float* Sg  = ws + 28*BN;                 // 8 floats
    unsigned* bar = (unsigned*)(Sg + 8);     // cnt[8] | gen[8]

    hipMemsetAsync(Sg, 0, 24*sizeof(unsigned), stream);   // S + barrier state
    emd_iter<<<dim3(512), dim3(512), 0, stream>>>(xyz1, xyz2, ws, out, Sg, bar);
    const float c8 = -(float)(0.25 * 1.4426950408889634);
    match_kernel<<<dim3(B_*128), dim3(256), 0, stream>>>(xyz1, xyz2, ws, out, c8);
}